// Round 4
// baseline (630.023 us; speedup 1.0000x reference)
//
#include <hip/hip_runtime.h>
#include <cstdint>
#include <cstddef>

// Problem constants (from reference)
#define TLEN 64
#define BSZ  32
#define NROW 2048           // TLEN*BSZ
#define HID  1024
#define SLEN 200
#define VT   32000
#define VE   2000
#define OUTW 34000          // VT + VE

// GEMM tiling: A-resident flatmm. 256x256 tile, A in LDS (K=128 chunks,
// double-buffered), B streamed global->reg, 8 waves (2M x 4N).
#define BM 256
#define BN 256
#define CHK 128             // K per LDS chunk
#define NMT 8               // NROW / BM
#define NNT 125             // VT / BN
#define NBN 125             // partials per row (one per bn tile)

typedef float  f32x4  __attribute__((ext_vector_type(4)));
typedef __bf16 bf16x4 __attribute__((ext_vector_type(4)));
typedef __bf16 bf16x8 __attribute__((ext_vector_type(8)));
typedef float  floatx4 __attribute__((ext_vector_type(4)));

// ---------------------------------------------------------------- prep
// blocks [0,2048): gate for row b + hidden->bf16
// blocks [2048,6144): grid-stride W f32->bf16
__global__ __launch_bounds__(256) void prep_kernel(
    const float* __restrict__ h, const float* __restrict__ wc,
    const float* __restrict__ bc, const float* __restrict__ W,
    __bf16* __restrict__ Hbf, __bf16* __restrict__ Wbf,
    float* __restrict__ logcopy, float* __restrict__ oneminus) {
  int tid = threadIdx.x;
  if (blockIdx.x < NROW) {
    int row = blockIdx.x;
    f32x4 v  = ((const f32x4*)(h + (size_t)row * HID))[tid];
    f32x4 wv = ((const f32x4*)wc)[tid];
    bf16x4 o;
    o.x = (__bf16)v.x; o.y = (__bf16)v.y; o.z = (__bf16)v.z; o.w = (__bf16)v.w;
    ((bf16x4*)(Hbf + (size_t)row * HID))[tid] = o;
    float s = v.x * wv.x + v.y * wv.y + v.z * wv.z + v.w * wv.w;
    #pragma unroll
    for (int off = 32; off; off >>= 1) s += __shfl_down(s, off, 64);
    __shared__ float wsum[4];
    int lane = tid & 63, w = tid >> 6;
    if (lane == 0) wsum[w] = s;
    __syncthreads();
    if (tid == 0) {
      float x = wsum[0] + wsum[1] + wsum[2] + wsum[3] + bc[0];
      float pc = 1.f / (1.f + __expf(-x));
      float pcc = fminf(fmaxf(pc, 0.001f), 0.999f);
      logcopy[row]  = logf(pcc);
      oneminus[row] = 1.f - pc;   // unclipped, matches reference
    }
  } else {
    const int n4 = (VT * HID) / 4;
    int i = (blockIdx.x - NROW) * 256 + tid;
    for (; i < n4; i += 4096 * 256) {
      f32x4 v = __builtin_nontemporal_load(((const f32x4*)W) + i);
      bf16x4 o;
      o.x = (__bf16)v.x; o.y = (__bf16)v.y; o.z = (__bf16)v.z; o.w = (__bf16)v.w;
      ((bf16x4*)Wbf)[i] = o;
    }
  }
}

// ---------------------------------------------------------------- MFMA GEMM
// A-resident flatmm: A-tile (256 rows) lives in LDS in K=128 double-buffered
// chunks staged via global_load_lds (XOR-granule swizzle, both-sides rule);
// B-fragments load straight global->VGPR (16x64B segments, L2-served; B is
// HBM-fetched once: XCD-disjoint bn ranges via bijective swizzle). NO main
// loop barriers (2 per chunk only): waves drift freely, MFMA overlaps L2
// loads without lockstep. K-loop = 8 chunks x 4 kslices x {4 B-loads,
// 8 A-ds_reads, 32 MFMA}.
//
// Chunk ledger: stage chunk c+1 (8 gload_lds/thread) issued at kslice 0 of
// chunk c; full-chunk compute (~5000 cyc) covers the flight; vmcnt(0) +
// barrier at chunk end. Buffer c+1 overwrites buffer of c-1, whose ds_reads
// completed before the PREVIOUS barrier (compiler lgkmcnt before MFMA).
//
// LDS swizzle: chunk row = 128 elems = 16 granules of 16B. Read frag needs
// lanes at rows r0+(l&15), granule ks*4+(l>>4): linear layout -> 16-way
// bank conflict. physical granule = (lg & 8) | ((lg ^ (row&7)) & 7), applied
// on the gload_lds GLOBAL source (dest stays linear) and on the ds_read
// address: per-instruction distribution identical to the verified
// conflict-free round-3 kernel.
//
// Epilogue (verified): C/D col=lane&15, row=(lane>>4)*4+reg; bias add; plain
// stores (warm for finish); per-(row,bn) sumexp partial to out[.., VT+bn].

__device__ __forceinline__ void load_lds16(const __bf16* g, __bf16* s) {
  __builtin_amdgcn_global_load_lds(
      (const __attribute__((address_space(1))) void*)g,
      (__attribute__((address_space(3))) void*)s, 16, 0, 0);
}

__global__ __launch_bounds__(512) void gemm_kernel(
    const __bf16* __restrict__ A, const __bf16* __restrict__ B,
    const float* __restrict__ bias, float* __restrict__ out) {
  __shared__ __attribute__((aligned(16))) __bf16 Asb[2][BM * CHK];  // 2x64 KiB

  const int tid = threadIdx.x;
  // XCD-bijective swizzle: 1000 blocks = 8 XCDs x 125; bm fastest in chunk.
  const int swz = ((int)blockIdx.x & 7) * 125 + ((int)blockIdx.x >> 3);
  const int bm = swz & 7;         // 0..7
  const int bn = swz >> 3;        // 0..124

  // ---- staging geometry (8 gload_lds per thread per chunk)
  // load i: li = i*512+tid -> LDS granule li (linear dst), row = i*32+(tid>>4),
  // src granule g = tid&15 pre-swizzled: sg = (g&8) | ((g ^ (row&7))&7);
  // row&7 = (tid>>4)&7 for all i (32 = 0 mod 8) -> sg i-independent.
  const int g15 = tid & 15;
  const int sg = (g15 & 8) | ((g15 ^ ((tid >> 4) & 7)) & 7);
  const __bf16* asrc = A + (size_t)(bm * BM + (tid >> 4)) * HID + sg * 8;
  __bf16* adst0 = &Asb[0][tid * 8];
  __bf16* adst1 = &Asb[1][tid * 8];

#define STAGE8(dst, ktn) do {                                              \
    _Pragma("unroll")                                                      \
    for (int i_ = 0; i_ < 8; i_++)                                         \
      load_lds16(asrc + i_ * 32 * HID + (ktn), (dst) + i_ * 4096);         \
  } while (0)

  // ---- per-wave fragment geometry
  const int l = tid & 63, w = tid >> 6;
  const int wm = w & 1;            // row half (128)
  const int wn = w >> 1;           // col quarter (64)
  const int lr = l & 15, q = l >> 4;
  const int x7 = lr & 7;
  // A ds_read: row_local = wm*128 + i*16 + lr, granule lg = ks*4+q,
  // phys = (lg&8)|((lg^x7)&7)  (row&7 == x7 for all frag rows)
  const int aoffr = (wm * 128 + lr) * CHK;   // elems
  int gaK[4];
  #pragma unroll
  for (int ks = 0; ks < 4; ks++) {
    int lg = ks * 4 + q;
    gaK[ks] = ((lg & 8) | ((lg ^ x7) & 7)) * 8;
  }
  // B global base: col n = bn*256 + wn*64 + j*16 + lr, k = kt + ks*32 + q*8
  const __bf16* bp = B + (size_t)(bn * BN + wn * 64 + lr) * HID + q * 8;

  floatx4 acc[8][4] = {};

#define CHUNK(CUR, NXT, KTB, KTN, DOST) do {                               \
    const __bf16* Ar = (CUR) + aoffr;                                      \
    _Pragma("unroll")                                                      \
    for (int ks = 0; ks < 4; ks++) {                                       \
      bf16x8 bf[4], af[8];                                                 \
      _Pragma("unroll")                                                    \
      for (int j = 0; j < 4; j++)                                          \
        bf[j] = *(const bf16x8*)(bp + (KTB) + ks * 32 + j * 16 * HID);     \
      _Pragma("unroll")                                                    \
      for (int i = 0; i < 8; i++)                                          \
        af[i] = *(const bf16x8*)(Ar + i * 16 * CHK + gaK[ks]);             \
      if (ks == 0 && (DOST)) STAGE8(NXT, KTN);                             \
      _Pragma("unroll")                                                    \
      for (int i = 0; i < 8; i++)                                          \
        _Pragma("unroll")                                                  \
        for (int j = 0; j < 4; j++)                                        \
          acc[i][j] = __builtin_amdgcn_mfma_f32_16x16x32_bf16(             \
              af[i], bf[j], acc[i][j], 0, 0, 0);                           \
    }                                                                      \
    asm volatile("s_waitcnt vmcnt(0)" ::: "memory");                       \
    __builtin_amdgcn_s_barrier();                                          \
  } while (0)

  // prologue: chunk 0 -> buf 0
  STAGE8(adst0, 0);
  asm volatile("s_waitcnt vmcnt(0)" ::: "memory");
  __builtin_amdgcn_s_barrier();

  CHUNK(Asb[0], adst1, 0,   128, true);
  CHUNK(Asb[1], adst0, 128, 256, true);
  CHUNK(Asb[0], adst1, 256, 384, true);
  CHUNK(Asb[1], adst0, 384, 512, true);
  CHUNK(Asb[0], adst1, 512, 640, true);
  CHUNK(Asb[1], adst0, 640, 768, true);
  CHUNK(Asb[0], adst1, 768, 896, true);
  CHUNK(Asb[1], adst0, 896, 0,   false);

  // ---- epilogue. K-loop LDS dead; alias reduction buffer onto Asb.
  __syncthreads();                       // full fence before LDS reuse
  float* lS = (float*)Asb;               // [4][256] floats = 4 KiB

  const int col0 = bn * BN + wn * 64 + lr;
  const int row0 = bm * BM + wm * 128 + q * 4;
  float bv[4];
  #pragma unroll
  for (int j = 0; j < 4; j++) bv[j] = bias[col0 + j * 16];

  #pragma unroll
  for (int fi = 0; fi < 8; fi++) {
    #pragma unroll
    for (int r = 0; r < 4; r++) {
      int m = row0 + fi * 16 + r;
      float* po = out + (size_t)m * OUTW + col0;
      float vj[4];
      #pragma unroll
      for (int j = 0; j < 4; j++) vj[j] = acc[fi][j][r] + bv[j];
      #pragma unroll
      for (int j = 0; j < 4; j++) po[j * 16] = vj[j];  // plain: warm for finish
      // sum-exp partial over this wave's 64 cols (logits bounded: no max pass)
      float s4 = __expf(vj[0]) + __expf(vj[1]) + __expf(vj[2]) + __expf(vj[3]);
      #pragma unroll
      for (int off = 1; off < 16; off <<= 1) s4 += __shfl_xor(s4, off, 64);
      if (lr == 0) lS[wn * BM + wm * 128 + fi * 16 + q * 4 + r] = s4;
    }
  }
  __syncthreads();
  if (tid < BM) {
    float S = lS[tid] + lS[BM + tid] + lS[2 * BM + tid] + lS[3 * BM + tid];
    out[(size_t)(bm * BM + tid) * OUTW + VT + bn] = S;
  }
#undef CHUNK
#undef STAGE8
}

// ---------------------------------------------------------------- finish
// Per row: (1) sum 125 partials -> sub = log(sumexp) - logcopy;
// (2) ext scatter into LDS; (3) out[row,0:VT] -= sub; (4) write log(clip(ext)).
__global__ __launch_bounds__(256) void finish_kernel(
    const float* __restrict__ attn, const int* __restrict__ c2e,
    const float* __restrict__ logcopy, const float* __restrict__ oneminus,
    float* __restrict__ out) {
  __shared__ float ext[VE];       // 8 KiB
  __shared__ float rS[4];
  int row = blockIdx.x;
  int tid = threadIdx.x;
  int b = row & (BSZ - 1);
  float* orow = out + (size_t)row * OUTW;

  // phase 1a: issue partial loads first (hide latency under ext zeroing)
  float S = (tid < NBN) ? orow[VT + tid] : 0.f;

  for (int e = tid; e < VE; e += 256) ext[e] = 0.f;

  // phase 1b: reduce partials
  #pragma unroll
  for (int off = 32; off; off >>= 1) S += __shfl_down(S, off, 64);
  int lane = tid & 63, w = tid >> 6;
  if (lane == 0) rS[w] = S;
  __syncthreads();
  float sub = logf(rS[0] + rS[1] + rS[2] + rS[3]) - logcopy[row];

  // phase 2: ext scatter into LDS
  float om1 = oneminus[row];
  if (tid < SLEN) {
    int idx = c2e[tid * BSZ + b];
    if (idx != 0)
      atomicAdd(&ext[idx], attn[(size_t)row * SLEN + tid] * om1);
  }

  // phase 3: subtract over generator vocab (cols 0..VT).
  // Plain loads (L2/L3 may still hold gemm's stores); NT stores (no reuse).
  #pragma unroll 4
  for (int k2 = 0; k2 < 31; k2++) {
    f32x4* p = (f32x4*)orow + (tid + k2 * 256);
    f32x4 v = *p;
    v = v - sub;
    __builtin_nontemporal_store(v, p);
  }
  {
    float v = orow[31744 + tid];
    __builtin_nontemporal_store(v - sub, orow + 31744 + tid);
  }

  __syncthreads();  // scatter complete
  for (int e = tid; e < VE; e += 256)
    __builtin_nontemporal_store(logf(fminf(fmaxf(ext[e], 0.001f), 0.999f)),
                                orow + VT + e);
}

// ---------------------------------------------------------------- launch
extern "C" void kernel_launch(void* const* d_in, const int* in_sizes, int n_in,
                              void* d_out, int out_size, void* d_ws, size_t ws_size,
                              hipStream_t stream) {
  const float* hidden = (const float*)d_in[0];   // [64,32,1024]
  const float* attn   = (const float*)d_in[1];   // [64,32,200]
  const int*   c2e    = (const int*)d_in[2];     // [200,32]
  const float* W      = (const float*)d_in[3];   // [32000,1024]
  const float* bout   = (const float*)d_in[4];   // [32000]
  const float* wc     = (const float*)d_in[5];   // [1024]
  const float* bc     = (const float*)d_in[6];   // [1]
  float* out = (float*)d_out;

  char* ws = (char*)d_ws;
  __bf16* Hbf = (__bf16*)ws;                              //  4,194,304 B
  __bf16* Wbf = (__bf16*)(ws + 4194304);                  // 65,536,000 B
  float* logcopy  = (float*)(ws + 4194304 + 65536000);    // 2048 f32
  float* oneminus = logcopy + NROW;                       // 2048 f32

  prep_kernel<<<NROW + 4096, 256, 0, stream>>>(hidden, wc, bc, W, Hbf, Wbf,
                                               logcopy, oneminus);
  gemm_kernel<<<NMT * NNT, 512, 0, stream>>>(Hbf, Wbf, bout, out);
  finish_kernel<<<NROW, 256, 0, stream>>>(attn, c2e, logcopy, oneminus, out);
}